// Round 3
// baseline (919.108 us; speedup 1.0000x reference)
//
#include <hip/hip_runtime.h>

#define NF 32       // IN_FEATS == OUT_FEATS == 32
#define BSHIFT 7    // 128 nodes per bucket
#define BNODES (1 << BSHIFT)

// Pass 1: per-edge: global deg histogram + LDS-aggregated bucket histogram.
__global__ void hist_kernel(const int* __restrict__ dst, int* __restrict__ deg,
                            int* __restrict__ bcount, int n_edges, int nb) {
    __shared__ int lh[1024];
    int t = threadIdx.x;
    for (int k = t; k < nb; k += 256) lh[k] = 0;
    __syncthreads();
    for (int e = blockIdx.x * 256 + t; e < n_edges; e += gridDim.x * 256) {
        int d = dst[e];
        atomicAdd(&deg[d], 1);
        atomicAdd(&lh[d >> BSHIFT], 1);
    }
    __syncthreads();
    for (int k = t; k < nb; k += 256) {
        int c = lh[k];
        if (c) atomicAdd(&bcount[k], c);
    }
}

// Pass 2: exclusive scan of bucket counts (nb <= 1024), one block.
__global__ void scan_kernel(const int* __restrict__ bcount, int* __restrict__ bstart,
                            int* __restrict__ cursor, int nb, int n_edges) {
    __shared__ int lds[1024];
    int t = threadIdx.x;
    int v = (t < nb) ? bcount[t] : 0;
    lds[t] = v;
    __syncthreads();
    for (int off = 1; off < 1024; off <<= 1) {
        int x = (t >= off) ? lds[t - off] : 0;
        __syncthreads();
        lds[t] += x;
        __syncthreads();
    }
    if (t < nb) {
        int ex = lds[t] - v;
        bstart[t] = ex;
        cursor[t] = ex;
    }
    if (t == 0) bstart[nb] = n_edges;
}

// Pass 3: bucket-place. One packed uint per edge: (src << 7) | (dst & 127).
// Writes advance sequentially within each of the 782 bucket streams -> good line merge.
__global__ void place_kernel(const int* __restrict__ src, const int* __restrict__ dst,
                             int* __restrict__ cursor, unsigned* __restrict__ pairs,
                             int n_edges) {
    int e = blockIdx.x * 256 + threadIdx.x;
    if (e < n_edges) {
        int d = dst[e];
        int pos = atomicAdd(&cursor[d >> BSHIFT], 1);
        pairs[pos] = ((unsigned)src[e] << BSHIFT) | (unsigned)(d & (BNODES - 1));
    }
}

// Projection: h[n] = (x[n] * rsqrt(deg+1)) @ W^T ; also writes isd.
__global__ void proj_kernel(const float* __restrict__ x, const float* __restrict__ W,
                            const int* __restrict__ deg, float* __restrict__ isd,
                            float* __restrict__ h, int n_nodes) {
    __shared__ float sWt[NF * NF];
    int t = threadIdx.x;
    for (int k = t; k < NF * NF; k += 256) sWt[k] = W[(k & 31) * NF + (k >> 5)];
    __syncthreads();
    int node = blockIdx.x * 8 + (t >> 5);
    int o = t & 31;
    if (node < n_nodes) {
        float s = rsqrtf((float)(deg[node] + 1));  // +1 self-loop; >= 1 always
        if (o == 0) isd[node] = s;
        const float* xr = x + (size_t)node * NF;
        float acc = 0.f;
#pragma unroll
        for (int i = 0; i < NF; i++) acc = fmaf(xr[i], sWt[i * NF + o], acc);
        h[node * NF + o] = acc * s;
    }
}

// Pass 4: one block per bucket. LDS accumulator (128 nodes x 32 feats = 16 KB).
// Edge loop: independent iterations (h-row gather + fire-and-forget LDS atomic)
// -> loads pipeline, no dependent-latency chain. Finalize fused.
__global__ void agg_kernel(const unsigned* __restrict__ pairs, const int* __restrict__ bstart,
                           const float* __restrict__ h, const float* __restrict__ isd,
                           const float* __restrict__ bias, float* __restrict__ out,
                           int n_nodes) {
    __shared__ float acc[BNODES * NF];  // 16 KB
    int b = blockIdx.x;
    int t = threadIdx.x;
    int node0 = b << BSHIFT;
    int nloc = min(BNODES, n_nodes - node0);
    // init with self-loop contribution h[node]
    for (int k = t; k < nloc * NF; k += 256) acc[k] = h[node0 * NF + k];
    __syncthreads();
    int s0 = bstart[b], s1 = bstart[b + 1];
    int g = t >> 5, o = t & 31;  // 8 groups of 32 lanes; lane o = feature
    int e = s0 + g;
    // 2x unrolled: two h-row loads in flight per group
    for (; e + 8 < s1; e += 16) {
        unsigned u0 = pairs[e];
        unsigned u1 = pairs[e + 8];
        float v0 = h[(u0 >> BSHIFT) * NF + o];
        float v1 = h[(u1 >> BSHIFT) * NF + o];
        atomicAdd(&acc[((u0 & (BNODES - 1)) << 5) + o], v0);
        atomicAdd(&acc[((u1 & (BNODES - 1)) << 5) + o], v1);
    }
    for (; e < s1; e += 8) {
        unsigned u = pairs[e];
        float v = h[(u >> BSHIFT) * NF + o];
        atomicAdd(&acc[((u & (BNODES - 1)) << 5) + o], v);
    }
    __syncthreads();
    // finalize: out = relu(acc * isd + bias)
    for (int k = t; k < nloc * NF; k += 256) {
        int n = node0 + (k >> 5);
        float v = fmaf(acc[k], isd[n], bias[k & 31]);
        out[n * NF + (k & 31)] = fmaxf(v, 0.f);
    }
}

extern "C" void kernel_launch(void* const* d_in, const int* in_sizes, int n_in,
                              void* d_out, int out_size, void* d_ws, size_t ws_size,
                              hipStream_t stream) {
    const float* feature = (const float*)d_in[0];
    const int*   src     = (const int*)d_in[1];
    const int*   dst     = (const int*)d_in[2];
    const float* W       = (const float*)d_in[3];
    const float* bias    = (const float*)d_in[4];
    float* out = (float*)d_out;

    int n_nodes = in_sizes[0] / NF;
    int n_edges = in_sizes[1];
    int nb = (n_nodes + BNODES - 1) >> BSHIFT;  // 782 buckets

    char* ws = (char*)d_ws;
    size_t off = 0;
    int* deg = (int*)(ws + off);        off += ((size_t)n_nodes * 4 + 255) & ~(size_t)255;
    int* bcount = (int*)(ws + off);     off += ((size_t)(nb + 1) * 4 + 255) & ~(size_t)255;
    int* bstart = (int*)(ws + off);     off += ((size_t)(nb + 1) * 4 + 255) & ~(size_t)255;
    int* cursor = (int*)(ws + off);     off += ((size_t)(nb + 1) * 4 + 255) & ~(size_t)255;
    float* isd = (float*)(ws + off);    off += ((size_t)n_nodes * 4 + 255) & ~(size_t)255;
    unsigned* pairs = (unsigned*)(ws + off); off += ((size_t)n_edges * 4 + 255) & ~(size_t)255;
    float* h = (float*)(ws + off);

    hipMemsetAsync(deg, 0, (size_t)n_nodes * 4, stream);
    hipMemsetAsync(bcount, 0, (size_t)(nb + 1) * 4, stream);

    hist_kernel<<<1024, 256, 0, stream>>>(dst, deg, bcount, n_edges, nb);
    scan_kernel<<<1, 1024, 0, stream>>>(bcount, bstart, cursor, nb, n_edges);
    place_kernel<<<(n_edges + 255) / 256, 256, 0, stream>>>(src, dst, cursor, pairs, n_edges);
    proj_kernel<<<(n_nodes + 7) / 8, 256, 0, stream>>>(feature, W, deg, isd, h, n_nodes);
    agg_kernel<<<nb, 256, 0, stream>>>(pairs, bstart, h, isd, bias, out, n_nodes);
}

// Round 4
// 529.735 us; speedup vs baseline: 1.7350x; 1.7350x over previous
//
#include <hip/hip_runtime.h>

#define NF 32       // IN_FEATS == OUT_FEATS == 32
#define BSHIFT 6    // 64 nodes per bucket
#define BNODES (1 << BSHIFT)

// Stage 1: in-degree histogram (100k addresses -> low contention).
__global__ void deg_kernel(const int* __restrict__ dst, int* __restrict__ deg, int n_edges) {
    int i = blockIdx.x * 256 + threadIdx.x;
    if (i < n_edges) atomicAdd(&deg[dst[i]], 1);
}

// Stage 2: bucket counts from deg via wave reduction (no atomics).
// One 64-lane wave per bucket; 4 buckets per 256-thread block.
__global__ void bsum_kernel(const int* __restrict__ deg, int* __restrict__ bcount,
                            int n_nodes, int nb) {
    int b = blockIdx.x * 4 + (threadIdx.x >> 6);
    if (b >= nb) return;
    int lane = threadIdx.x & 63;
    int node = (b << BSHIFT) + lane;
    int v = (node < n_nodes) ? deg[node] : 0;
#pragma unroll
    for (int off = 32; off; off >>= 1) v += __shfl_down(v, off, 64);
    if (lane == 0) bcount[b] = v;
}

// Stage 3: exclusive scan of bucket counts (nb <= 2048), one block, 2 elems/thread.
__global__ void scan_kernel(const int* __restrict__ bcount, int* __restrict__ bstart,
                            int* __restrict__ cursor, int nb, int n_edges) {
    __shared__ int lds[1024];
    int t = threadIdx.x;
    int i0 = 2 * t, i1 = 2 * t + 1;
    int v0 = (i0 < nb) ? bcount[i0] : 0;
    int v1 = (i1 < nb) ? bcount[i1] : 0;
    int s = v0 + v1;
    lds[t] = s;
    __syncthreads();
    for (int off = 1; off < 1024; off <<= 1) {
        int x = (t >= off) ? lds[t - off] : 0;
        __syncthreads();
        lds[t] += x;
        __syncthreads();
    }
    int ex = lds[t] - s;
    if (i0 < nb) { bstart[i0] = ex;      cursor[i0] = ex; }
    if (i1 < nb) { bstart[i1] = ex + v0; cursor[i1] = ex + v0; }
    if (t == 0) bstart[nb] = n_edges;
}

// Stage 4: bucket-place, per-block two-pass.
// (a) LDS-histogram this block's edge chunk; (b) reserve a contiguous run per bucket
// with ONE global atomic per (block,bucket); (c) place edges via LDS cursors.
// Packed edge: (src << 6) | (dst & 63)  (src < 2^17 -> fits 23 bits).
__global__ void place_kernel(const int* __restrict__ src, const int* __restrict__ dst,
                             int* __restrict__ cursor, unsigned* __restrict__ pairs,
                             int n_edges, int epb, int nb) {
    __shared__ int lc[2048];
    int t = threadIdx.x;
    for (int k = t; k < nb; k += 256) lc[k] = 0;
    __syncthreads();
    int ebeg = blockIdx.x * epb;
    int eend = min(n_edges, ebeg + epb);
    for (int e = ebeg + t; e < eend; e += 256) atomicAdd(&lc[dst[e] >> BSHIFT], 1);
    __syncthreads();
    for (int k = t; k < nb; k += 256) {
        int c = lc[k];
        lc[k] = c ? atomicAdd(&cursor[k], c) : 0;  // count -> global base
    }
    __syncthreads();
    for (int e = ebeg + t; e < eend; e += 256) {
        int d = dst[e];
        int pos = atomicAdd(&lc[d >> BSHIFT], 1);  // LDS cursor
        pairs[pos] = ((unsigned)src[e] << BSHIFT) | (unsigned)(d & (BNODES - 1));
    }
}

// Stage 5: h[n] = (x[n] * rsqrt(deg+1)) @ W^T ; also writes isd.
__global__ void proj_kernel(const float* __restrict__ x, const float* __restrict__ W,
                            const int* __restrict__ deg, float* __restrict__ isd,
                            float* __restrict__ h, int n_nodes) {
    __shared__ float sWt[NF * NF];
    int t = threadIdx.x;
    for (int k = t; k < NF * NF; k += 256) sWt[k] = W[(k & 31) * NF + (k >> 5)];
    __syncthreads();
    int node = blockIdx.x * 8 + (t >> 5);
    int o = t & 31;
    if (node < n_nodes) {
        float s = rsqrtf((float)(deg[node] + 1));  // +1 self-loop
        if (o == 0) isd[node] = s;
        const float* xr = x + (size_t)node * NF;
        float acc = 0.f;
#pragma unroll
        for (int i = 0; i < NF; i++) acc = fmaf(xr[i], sWt[i * NF + o], acc);
        h[node * NF + o] = acc * s;
    }
}

// Stage 6: one block per 64-node bucket, 8 KB LDS accumulator, 4x-unrolled edge loop
// (4 independent 128B gathers in flight per 32-lane group). Finalize fused.
__global__ void agg_kernel(const unsigned* __restrict__ pairs, const int* __restrict__ bstart,
                           const float* __restrict__ h, const float* __restrict__ isd,
                           const float* __restrict__ bias, float* __restrict__ out,
                           int n_nodes) {
    __shared__ float acc[BNODES * NF];  // 8 KB
    int b = blockIdx.x;
    int t = threadIdx.x;
    int node0 = b << BSHIFT;
    int total = min(BNODES, n_nodes - node0) * NF;
    for (int k = t; k < total; k += 256) acc[k] = h[node0 * NF + k];  // self-loop init
    __syncthreads();
    int s0 = bstart[b], s1 = bstart[b + 1];
    int g = t >> 5, o = t & 31;  // 8 groups of 32 lanes; lane = feature
    int e = s0 + g;
    for (; e + 24 < s1; e += 32) {
        unsigned u0 = pairs[e];
        unsigned u1 = pairs[e + 8];
        unsigned u2 = pairs[e + 16];
        unsigned u3 = pairs[e + 24];
        float v0 = h[(u0 >> BSHIFT) * NF + o];
        float v1 = h[(u1 >> BSHIFT) * NF + o];
        float v2 = h[(u2 >> BSHIFT) * NF + o];
        float v3 = h[(u3 >> BSHIFT) * NF + o];
        atomicAdd(&acc[((u0 & (BNODES - 1)) << 5) + o], v0);
        atomicAdd(&acc[((u1 & (BNODES - 1)) << 5) + o], v1);
        atomicAdd(&acc[((u2 & (BNODES - 1)) << 5) + o], v2);
        atomicAdd(&acc[((u3 & (BNODES - 1)) << 5) + o], v3);
    }
    for (; e < s1; e += 8) {
        unsigned u = pairs[e];
        atomicAdd(&acc[((u & (BNODES - 1)) << 5) + o], h[(u >> BSHIFT) * NF + o]);
    }
    __syncthreads();
    for (int k = t; k < total; k += 256) {
        int n = node0 + (k >> 5);
        float v = fmaf(acc[k], isd[n], bias[k & 31]);
        out[n * NF + (k & 31)] = fmaxf(v, 0.f);
    }
}

extern "C" void kernel_launch(void* const* d_in, const int* in_sizes, int n_in,
                              void* d_out, int out_size, void* d_ws, size_t ws_size,
                              hipStream_t stream) {
    const float* feature = (const float*)d_in[0];
    const int*   src     = (const int*)d_in[1];
    const int*   dst     = (const int*)d_in[2];
    const float* W       = (const float*)d_in[3];
    const float* bias    = (const float*)d_in[4];
    float* out = (float*)d_out;

    int n_nodes = in_sizes[0] / NF;
    int n_edges = in_sizes[1];
    int nb = (n_nodes + BNODES - 1) >> BSHIFT;  // 1563 buckets

    char* ws = (char*)d_ws;
    size_t off = 0;
    int* deg = (int*)(ws + off);        off += ((size_t)n_nodes * 4 + 255) & ~(size_t)255;
    int* bcount = (int*)(ws + off);     off += ((size_t)(nb + 1) * 4 + 255) & ~(size_t)255;
    int* bstart = (int*)(ws + off);     off += ((size_t)(nb + 1) * 4 + 255) & ~(size_t)255;
    int* cursor = (int*)(ws + off);     off += ((size_t)(nb + 1) * 4 + 255) & ~(size_t)255;
    float* isd = (float*)(ws + off);    off += ((size_t)n_nodes * 4 + 255) & ~(size_t)255;
    unsigned* pairs = (unsigned*)(ws + off); off += ((size_t)n_edges * 4 + 255) & ~(size_t)255;
    float* h = (float*)(ws + off);

    hipMemsetAsync(deg, 0, (size_t)n_nodes * 4, stream);

    deg_kernel<<<(n_edges + 255) / 256, 256, 0, stream>>>(dst, deg, n_edges);
    bsum_kernel<<<(nb + 3) / 4, 256, 0, stream>>>(deg, bcount, n_nodes, nb);
    scan_kernel<<<1, 1024, 0, stream>>>(bcount, bstart, cursor, nb, n_edges);

    int place_blocks = 128;
    int epb = (n_edges + place_blocks - 1) / place_blocks;
    place_kernel<<<place_blocks, 256, 0, stream>>>(src, dst, cursor, pairs, n_edges, epb, nb);

    proj_kernel<<<(n_nodes + 7) / 8, 256, 0, stream>>>(feature, W, deg, isd, h, n_nodes);

    agg_kernel<<<nb, 256, 0, stream>>>(pairs, bstart, h, isd, bias, out, n_nodes);
}